// Round 1
// baseline (194.565 us; speedup 1.0000x reference)
//
#include <hip/hip_runtime.h>
#include <hip/hip_bf16.h>

typedef __hip_bfloat16 bf16;
typedef __attribute__((ext_vector_type(8))) short short8;   // 8 bf16 = one MFMA A/B frag
typedef __attribute__((ext_vector_type(4))) float f32x4;    // MFMA C/D frag

#define MFMA(a, b, c) __builtin_amdgcn_mfma_f32_16x16x32_bf16(a, b, c, 0, 0, 0)

static __device__ __forceinline__ float b2f(unsigned short u) {
  union { unsigned u; float f; } t; t.u = ((unsigned)u) << 16; return t.f;
}
static __device__ __forceinline__ unsigned short f2bf(float f) {
  union { float f; unsigned u; } t; t.f = f;
  unsigned r = t.u + 0x7fffu + ((t.u >> 16) & 1u);   // RNE
  return (unsigned short)(r >> 16);
}
static __device__ __forceinline__ unsigned pack2(float a, float b) {
  return (unsigned)f2bf(a) | ((unsigned)f2bf(b) << 16);
}
// packed f32x2 -> bf16x2 (RNE); lo -> low 16 bits. Compiler may emit v_cvt_pk_bf16_f32.
static __device__ __forceinline__ unsigned pack_bf2(float lo, float hi) {
  __hip_bfloat162 h = __float22bfloat162_rn(float2{lo, hi});
  union { __hip_bfloat162 h; unsigned u; } c; c.h = h; return c.u;
}

// ---- workspace layout (bf16 element offsets) ----
#define KB_OFF   ((size_t)0)          // K  [2048][1024]
#define QB_OFF   ((size_t)2097152)    // Q  [2048][1024]
#define G1_OFF   ((size_t)4194304)    // G1 [2048][1024]
#define G2_OFF   ((size_t)6291456)    // G2 [2048][1024]
#define VT_OFF   ((size_t)8388608)    // V^T [512][2048]
#define WT_BASE  ((size_t)9437184)
#define WTK_OFF  (WT_BASE)                       // [1024][512]
#define WTQ_OFF  (WT_BASE + (size_t)524288)
#define WTG1_OFF (WT_BASE + (size_t)1048576)
#define WTG2_OFF (WT_BASE + (size_t)1572864)
#define WTV_OFF  (WT_BASE + (size_t)2097152)     // [512][512]
// After proj, the WT region is dead -> reuse for attention partials:
#define NUM0_OFF (WT_BASE)                       // bf16 [2048][512] (n-split 0)
#define NUM1_OFF (WT_BASE + (size_t)1048576)     // bf16 [2048][512] (n-split 1)
#define DEN_OFF  (WT_BASE + (size_t)2097152)     // f32  [2][8][2048] (as raw bytes)
#define VSUM_OFF (DEN_OFF + (size_t)65536)       // f32  [512] column sums of V
// total ws: 11,796,480 bf16 elems = 23.6 MB (unchanged)

// LDS XOR swizzles (byte-address based, applied identically on write & read)
#define KSWZ(r, cB) ((((r) * 256) + (cB)) ^ ((((r) & 7)) << 4))   // [64][128] bf16 tiles
#define PSWZ(r, cB) ((((r) * 128) + (cB)) ^ ((((r) & 7)) << 4))   // [16][64] bf16 tile

// Transpose + convert W[k][n] fp32 -> Wt[n][k] bf16, all 5 weights in one launch.
__global__ __launch_bounds__(256)
void wtrans_kernel(const float* __restrict__ WK, const float* __restrict__ WQ,
                   const float* __restrict__ WG1, const float* __restrict__ WG2,
                   const float* __restrict__ WV, bf16* __restrict__ ws)
{
  __shared__ float T[32][33];
  const float* W; unsigned short* Wt; int N;
  switch (blockIdx.z) {
    case 0:  W = WK;  Wt = (unsigned short*)(ws + WTK_OFF);  N = 1024; break;
    case 1:  W = WQ;  Wt = (unsigned short*)(ws + WTQ_OFF);  N = 1024; break;
    case 2:  W = WG1; Wt = (unsigned short*)(ws + WTG1_OFF); N = 1024; break;
    case 3:  W = WG2; Wt = (unsigned short*)(ws + WTG2_OFF); N = 1024; break;
    default: W = WV;  Wt = (unsigned short*)(ws + WTV_OFF);  N = 512;  break;
  }
  int n0 = blockIdx.x * 32, k0 = blockIdx.y * 32;
  if (n0 >= N) return;
  int tid = threadIdx.x;
  int kk = tid >> 3, nn = (tid & 7) * 4;
  float4 v = *(const float4*)(W + (size_t)(k0 + kk) * N + n0 + nn);
  T[kk][nn] = v.x; T[kk][nn + 1] = v.y; T[kk][nn + 2] = v.z; T[kk][nn + 3] = v.w;
  __syncthreads();
  int n2 = tid >> 3, k2 = (tid & 7) * 4;
  uint2 pw;
  pw.x = pack2(T[k2][n2],     T[k2 + 1][n2]);
  pw.y = pack2(T[k2 + 2][n2], T[k2 + 3][n2]);
  *(uint2*)(Wt + (size_t)(n0 + n2) * 512 + k0 + k2) = pw;
}

// Batched MFMA projection GEMM (verified round 4).
__global__ __launch_bounds__(256)
void proj_mfma_kernel(const float* __restrict__ fa, const float* __restrict__ fp,
                      const float* __restrict__ sa, const float* __restrict__ sp,
                      const float* __restrict__ bKp, const float* __restrict__ bQp,
                      const float* __restrict__ bG1p, const float* __restrict__ bG2p,
                      const float* __restrict__ bVp, bf16* __restrict__ ws)
{
  __shared__ short Xs[128][40];
  __shared__ short Wsh[128][40];
  const float* X; const unsigned short* Wt; const float* bias; unsigned short* C;
  int N; bool trans = false;
  switch (blockIdx.z) {
    case 0:  X = fa; Wt = (const unsigned short*)(ws + WTK_OFF);  bias = bKp;  C = (unsigned short*)(ws + KB_OFF); N = 1024; break;
    case 1:  X = sa; Wt = (const unsigned short*)(ws + WTQ_OFF);  bias = bQp;  C = (unsigned short*)(ws + QB_OFF); N = 1024; break;
    case 2:  X = fp; Wt = (const unsigned short*)(ws + WTG1_OFF); bias = bG1p; C = (unsigned short*)(ws + G1_OFF); N = 1024; break;
    case 3:  X = sp; Wt = (const unsigned short*)(ws + WTG2_OFF); bias = bG2p; C = (unsigned short*)(ws + G2_OFF); N = 1024; break;
    default: X = fa; Wt = (const unsigned short*)(ws + WTV_OFF);  bias = bVp;  C = (unsigned short*)(ws + VT_OFF); N = 512; trans = true; break;
  }
  const int n0 = blockIdx.x * 128;
  if (n0 >= N) return;
  const int m0 = blockIdx.y * 128;
  const int tid = threadIdx.x;
  const int w = tid >> 6, l = tid & 63, l15 = l & 15, l4 = l >> 4;
  const int wm = (w & 1) * 64, wn = (w >> 1) * 64;
  const int srow = tid >> 1, shalf = (tid & 1) * 16;

  const float* xp = X + (size_t)(m0 + srow) * 512 + shalf;
  const unsigned short* wp = Wt + (size_t)(n0 + srow) * 512 + shalf;

  const f32x4 zero = {0.f, 0.f, 0.f, 0.f};
  f32x4 acc[4][4];
#pragma unroll
  for (int i = 0; i < 4; ++i)
#pragma unroll
    for (int j = 0; j < 4; ++j) acc[i][j] = zero;

  float4 px[4]; uint4 pw0, pw1;
  auto ldg = [&](int kc) {
    px[0] = *(const float4*)(xp + kc);
    px[1] = *(const float4*)(xp + kc + 4);
    px[2] = *(const float4*)(xp + kc + 8);
    px[3] = *(const float4*)(xp + kc + 12);
    pw0 = *(const uint4*)(wp + kc);
    pw1 = *(const uint4*)(wp + kc + 8);
  };
  ldg(0);

  for (int kc = 0; kc < 512; kc += 32) {
    __syncthreads();
    uint4 xa, xb;
    xa.x = pack2(px[0].x, px[0].y); xa.y = pack2(px[0].z, px[0].w);
    xa.z = pack2(px[1].x, px[1].y); xa.w = pack2(px[1].z, px[1].w);
    xb.x = pack2(px[2].x, px[2].y); xb.y = pack2(px[2].z, px[2].w);
    xb.z = pack2(px[3].x, px[3].y); xb.w = pack2(px[3].z, px[3].w);
    *(uint4*)&Xs[srow][shalf]      = xa;
    *(uint4*)&Xs[srow][shalf + 8]  = xb;
    *(uint4*)&Wsh[srow][shalf]     = pw0;
    *(uint4*)&Wsh[srow][shalf + 8] = pw1;
    __syncthreads();
    if (kc + 32 < 512) ldg(kc + 32);

    short8 xf[4], wf[4];
#pragma unroll
    for (int t = 0; t < 4; ++t) {
      xf[t] = *(const short8*)&Xs[wm + t * 16 + l15][l4 * 8];
      wf[t] = *(const short8*)&Wsh[wn + t * 16 + l15][l4 * 8];
    }
    if (!trans) {
#pragma unroll
      for (int i = 0; i < 4; ++i)
#pragma unroll
        for (int j = 0; j < 4; ++j)
          acc[i][j] = MFMA(wf[i], xf[j], acc[i][j]);   // D[n][m]
    } else {
#pragma unroll
      for (int i = 0; i < 4; ++i)
#pragma unroll
        for (int j = 0; j < 4; ++j)
          acc[i][j] = MFMA(xf[i], wf[j], acc[i][j]);   // D[m][n]
    }
  }

  if (!trans) {
#pragma unroll
    for (int tn = 0; tn < 4; ++tn) {
      float4 b4 = *(const float4*)(bias + n0 + wn + tn * 16 + l4 * 4);
#pragma unroll
      for (int tm = 0; tm < 4; ++tm) {
        uint2 pw;
        pw.x = pack2(acc[tn][tm][0] + b4.x, acc[tn][tm][1] + b4.y);
        pw.y = pack2(acc[tn][tm][2] + b4.z, acc[tn][tm][3] + b4.w);
        *(uint2*)(C + (size_t)(m0 + wm + tm * 16 + l15) * N + n0 + wn + tn * 16 + l4 * 4) = pw;
      }
    }
  } else {
#pragma unroll
    for (int tn = 0; tn < 4; ++tn) {
      float bn = bias[n0 + wn + tn * 16 + l15];
#pragma unroll
      for (int tm = 0; tm < 4; ++tm) {
        uint2 pw;
        pw.x = pack2(acc[tm][tn][0] + bn, acc[tm][tn][1] + bn);
        pw.y = pack2(acc[tm][tn][2] + bn, acc[tm][tn][3] + bn);
        *(uint2*)(C + (size_t)(n0 + wn + tn * 16 + l15) * 2048 + m0 + wm + tm * 16 + l4 * 4) = pw;
      }
    }
  }
}

// Column sums of V (= row sums of V^T [512][2048]) in f32. One wave per row.
__global__ __launch_bounds__(256)
void vsum_kernel(const bf16* __restrict__ Vtg, float* __restrict__ vs)
{
  const int row = blockIdx.x * 4 + (threadIdx.x >> 6);
  const int l = threadIdx.x & 63;
  const bf16* p = Vtg + (size_t)row * 2048 + l * 8;
  float s = 0.f;
#pragma unroll
  for (int c = 0; c < 4; ++c) {
    short8 v = *(const short8*)(p + c * 512);
#pragma unroll
    for (int j = 0; j < 8; ++j) s += b2f((unsigned short)v[j]);
  }
#pragma unroll
  for (int off = 32; off; off >>= 1) s += __shfl_xor(s, off, 64);
  if (l == 0) vs[row] = s;
}

// MFMA fused attention, operand-swapped scores:
//  - MFMA(K,Q)/MFMA(G1,G2) put S[n-local][m=l15] in each lane: every lane owns one
//    m-row with n-contiguous quads -> P' store is 4x ds_write_b64, reload is
//    2x ds_read_b128 (was 16 scalar ds_read_u16), scale is a per-lane register.
//  - V^T read directly from global (2 MB, L2-resident) -> no Vts staging/vsum.
//  - Ks/G1s [64][128] + byte-XOR swizzle (no padding), Ps [16][64]/wave swizzled.
//  - LDS 40960 B -> 4 blocks/CU (was 55808 B -> 2 blocks/CU).
__global__ __launch_bounds__(256, 4)
void attn_mfma_kernel(const bf16* __restrict__ Kb, const bf16* __restrict__ G1b,
                      const bf16* __restrict__ Vtg, const bf16* __restrict__ Qb,
                      const bf16* __restrict__ G2b, bf16* __restrict__ ws)
{
  __shared__ short Ks[64][128];
  __shared__ short G1s[64][128];
  __shared__ short Ps[4][16][64];

  const int tid = threadIdx.x;
  const int w   = tid >> 6;
  const int l   = tid & 63;
  const int l15 = l & 15;
  const int l4  = l >> 4;
  const int h   = blockIdx.y;
  const int m0  = blockIdx.x * 64;
  const int split = blockIdx.z;

  short8 qf[4], gf[4];
  {
    const size_t ro = (size_t)(m0 + w * 16 + l15) * 1024 + h * 128 + l4 * 8;
#pragma unroll
    for (int kk = 0; kk < 4; ++kk) {
      qf[kk] = *(const short8*)(Qb + ro + kk * 32);
      gf[kk] = *(const short8*)(G2b + ro + kk * 32);
    }
  }
  float sc;
  {
    float sq = 0.f, sg = 0.f;
#pragma unroll
    for (int kk = 0; kk < 4; ++kk)
#pragma unroll
      for (int j = 0; j < 8; ++j) {
        float q = b2f((unsigned short)qf[kk][j]);
        float g = b2f((unsigned short)gf[kk][j]);
        sq += q * q; sg += g * g;
      }
    sq += __shfl_xor(sq, 16, 64); sq += __shfl_xor(sq, 32, 64);
    sg += __shfl_xor(sg, 16, 64); sg += __shfl_xor(sg, 32, 64);
    // per-lane scale for row m = w*16 + l15 (all 16 of this lane's P' share it)
    sc = rsqrtf(sq) * rsqrtf(sg) * (1.0f / 16384.0f);
  }

  const int r0  = tid >> 3;
  const int c0  = (tid & 7) * 16;    // shorts
  const int c0b = c0 * 2;            // bytes

  short8 pk[4], pg[4];
  auto load_tile = [&](int nt) {     // nt in global 64-units
    const int n0 = nt * 64;
    const bf16* kp = Kb  + (size_t)(n0 + r0) * 1024 + h * 128 + c0;
    const bf16* gp = G1b + (size_t)(n0 + r0) * 1024 + h * 128 + c0;
    pk[0] = *(const short8*)(kp);
    pk[1] = *(const short8*)(kp + 8);
    pk[2] = *(const short8*)(kp + 32 * 1024);
    pk[3] = *(const short8*)(kp + 32 * 1024 + 8);
    pg[0] = *(const short8*)(gp);
    pg[1] = *(const short8*)(gp + 8);
    pg[2] = *(const short8*)(gp + 32 * 1024);
    pg[3] = *(const short8*)(gp + 32 * 1024 + 8);
  };
  const int ntbase = split * 16;
  load_tile(ntbase);

  const f32x4 zero = {0.f, 0.f, 0.f, 0.f};
  f32x4 accO[4], accD = zero;
#pragma unroll
  for (int t = 0; t < 4; ++t) accO[t] = zero;

  short8 ones;
#pragma unroll
  for (int j = 0; j < 8; ++j) ones[j] = (short)0x3F80;

  char* const ksb = (char*)&Ks[0][0];
  char* const g1p = (char*)&G1s[0][0];
  char* const psb = (char*)&Ps[w][0][0];
  const bf16* const vbase = Vtg + (size_t)(h * 64 + l15) * 2048 + l4 * 8;

  for (int nt = 0; nt < 16; ++nt) {
    __syncthreads();
    *(short8*)(ksb + KSWZ(r0,      c0b))      = pk[0];
    *(short8*)(ksb + KSWZ(r0,      c0b + 16)) = pk[1];
    *(short8*)(ksb + KSWZ(r0 + 32, c0b))      = pk[2];
    *(short8*)(ksb + KSWZ(r0 + 32, c0b + 16)) = pk[3];
    *(short8*)(g1p + KSWZ(r0,      c0b))      = pg[0];
    *(short8*)(g1p + KSWZ(r0,      c0b + 16)) = pg[1];
    *(short8*)(g1p + KSWZ(r0 + 32, c0b))      = pg[2];
    *(short8*)(g1p + KSWZ(r0 + 32, c0b + 16)) = pg[3];
    __syncthreads();
    if (nt + 1 < 16) load_tile(ntbase + nt + 1);

    const int n0g = (ntbase + nt) * 64;

    // scores for this tile: swapped operands -> lane holds S[n-quads][m=l15]
#pragma unroll
    for (int t = 0; t < 4; ++t) {
      f32x4 sa = zero, sg2 = zero;
#pragma unroll
      for (int kk = 0; kk < 4; ++kk) {
        short8 kbf = *(const short8*)(ksb + KSWZ(t * 16 + l15, kk * 64 + l4 * 16));
        sa  = MFMA(kbf, qf[kk], sa);
        short8 gbf = *(const short8*)(g1p + KSWZ(t * 16 + l15, kk * 64 + l4 * 16));
        sg2 = MFMA(gbf, gf[kk], sg2);
      }
      // P' = exp(x)-1 ~= x + x^2/2 (|x| ~ 1e-4)
      float x0 = sa[0] * sg2[0] * sc;
      float x1 = sa[1] * sg2[1] * sc;
      float x2 = sa[2] * sg2[2] * sc;
      float x3 = sa[3] * sg2[3] * sc;
      float p0 = __builtin_fmaf(0.5f * x0, x0, x0);
      float p1 = __builtin_fmaf(0.5f * x1, x1, x1);
      float p2 = __builtin_fmaf(0.5f * x2, x2, x2);
      float p3 = __builtin_fmaf(0.5f * x3, x3, x3);
      uint2 pw;
      pw.x = pack_bf2(p0, p1);
      pw.y = pack_bf2(p2, p3);
      // Ps[m=l15][n = t*16 + l4*4 .. +3]
      *(uint2*)(psb + PSWZ(l15, t * 32 + l4 * 8)) = pw;
    }

    // PV + denominator; V^T read straight from L2
#pragma unroll
    for (int ks = 0; ks < 2; ++ks) {
      short8 pf = *(const short8*)(psb + PSWZ(l15, ks * 64 + l4 * 16));
      accD = MFMA(pf, ones, accD);
      const bf16* vp = vbase + n0g + ks * 32;
#pragma unroll
      for (int jt = 0; jt < 4; ++jt) {
        short8 vbf = *(const short8*)(vp + (size_t)jt * 16 * 2048);
        accO[jt] = MFMA(pf, vbf, accO[jt]);
      }
    }
  }

  // ---- write partials ----
  bf16* num = ws + (split ? NUM1_OFF : NUM0_OFF);
  float* den = (float*)(ws + DEN_OFF);
  if (l15 == 0) {
#pragma unroll
    for (int r = 0; r < 4; ++r)
      den[(size_t)(split * 8 + h) * 2048 + m0 + w * 16 + l4 * 4 + r] = accD[r];
  }
#pragma unroll
  for (int jt = 0; jt < 4; ++jt) {
#pragma unroll
    for (int r = 0; r < 4; ++r)
      num[(size_t)(m0 + w * 16 + l4 * 4 + r) * 512 + h * 64 + jt * 16 + l15]
        = __float2bfloat16(accO[jt][r]);
  }
}

// out[m][c] = (num0+num1+Vsum[c]) / (2048 + den0 + den1), 8 elems/thread
__global__ __launch_bounds__(256)
void combine_kernel(const bf16* __restrict__ ws, float* __restrict__ out)
{
  const unsigned short* num0 = (const unsigned short*)(ws + NUM0_OFF);
  const unsigned short* num1 = (const unsigned short*)(ws + NUM1_OFF);
  const float* den  = (const float*)(ws + DEN_OFF);
  const float* vsum = (const float*)(ws + VSUM_OFF);
  int idx = (blockIdx.x * 256 + threadIdx.x) * 8;
  int m = idx >> 9, c = idx & 511, h = c >> 6;
  float d = 2048.0f + den[(size_t)h * 2048 + m] + den[(size_t)(8 + h) * 2048 + m];
  float rd = 1.0f / d;
  short8 a = *(const short8*)(num0 + idx);
  short8 b = *(const short8*)(num1 + idx);
  float4 v0 = *(const float4*)(vsum + c);
  float4 v1 = *(const float4*)(vsum + c + 4);
  float vs[8] = {v0.x, v0.y, v0.z, v0.w, v1.x, v1.y, v1.z, v1.w};
  float r[8];
#pragma unroll
  for (int j = 0; j < 8; ++j)
    r[j] = (b2f((unsigned short)a[j]) + b2f((unsigned short)b[j]) + vs[j]) * rd;
  *(float4*)(out + idx)     = float4{r[0], r[1], r[2], r[3]};
  *(float4*)(out + idx + 4) = float4{r[4], r[5], r[6], r[7]};
}

extern "C" void kernel_launch(void* const* d_in, const int* in_sizes, int n_in,
                              void* d_out, int out_size, void* d_ws, size_t ws_size,
                              hipStream_t stream) {
  const float* first_app  = (const float*)d_in[0];
  const float* first_pos  = (const float*)d_in[1];
  const float* second_app = (const float*)d_in[2];
  const float* second_pos = (const float*)d_in[3];
  const float* WK  = (const float*)d_in[4];
  const float* bK  = (const float*)d_in[5];
  const float* WQ  = (const float*)d_in[6];
  const float* bQ  = (const float*)d_in[7];
  const float* WV  = (const float*)d_in[8];
  const float* bV  = (const float*)d_in[9];
  const float* WG1 = (const float*)d_in[10];
  const float* bG1 = (const float*)d_in[11];
  const float* WG2 = (const float*)d_in[12];
  const float* bG2 = (const float*)d_in[13];

  bf16* ws = (bf16*)d_ws;

  wtrans_kernel<<<dim3(32, 16, 5), 256, 0, stream>>>(WK, WQ, WG1, WG2, WV, ws);
  proj_mfma_kernel<<<dim3(8, 16, 5), 256, 0, stream>>>(
      first_app, first_pos, second_app, second_pos, bK, bQ, bG1, bG2, bV, ws);
  vsum_kernel<<<dim3(128), 256, 0, stream>>>(ws + VT_OFF, (float*)(ws + VSUM_OFF));
  attn_mfma_kernel<<<dim3(32, 8, 2), 256, 0, stream>>>(
      ws + KB_OFF, ws + G1_OFF, ws + VT_OFF, ws + QB_OFF, ws + G2_OFF, ws);
  combine_kernel<<<dim3(512), 256, 0, stream>>>(ws, (float*)d_out);
}

// Round 2
// 177.051 us; speedup vs baseline: 1.0989x; 1.0989x over previous
//
#include <hip/hip_runtime.h>
#include <hip/hip_bf16.h>

typedef __hip_bfloat16 bf16;
typedef __attribute__((ext_vector_type(8))) short short8;   // 8 bf16 = one MFMA A/B frag
typedef __attribute__((ext_vector_type(4))) float f32x4;    // MFMA C/D frag

#define MFMA(a, b, c) __builtin_amdgcn_mfma_f32_16x16x32_bf16(a, b, c, 0, 0, 0)

static __device__ __forceinline__ float b2f(unsigned short u) {
  union { unsigned u; float f; } t; t.u = ((unsigned)u) << 16; return t.f;
}
static __device__ __forceinline__ unsigned short f2bf(float f) {
  union { float f; unsigned u; } t; t.f = f;
  unsigned r = t.u + 0x7fffu + ((t.u >> 16) & 1u);   // RNE
  return (unsigned short)(r >> 16);
}
static __device__ __forceinline__ unsigned pack2(float a, float b) {
  return (unsigned)f2bf(a) | ((unsigned)f2bf(b) << 16);
}
// packed f32x2 -> bf16x2 (RNE); lo -> low 16 bits.
static __device__ __forceinline__ unsigned pack_bf2(float lo, float hi) {
  __hip_bfloat162 h = __float22bfloat162_rn(float2{lo, hi});
  union { __hip_bfloat162 h; unsigned u; } c; c.h = h; return c.u;
}

// ---- workspace layout (bf16 element offsets) ----
#define KB_OFF   ((size_t)0)          // K  [2048][1024]
#define QB_OFF   ((size_t)2097152)    // Q  [2048][1024]
#define G1_OFF   ((size_t)4194304)    // G1 [2048][1024]
#define G2_OFF   ((size_t)6291456)    // G2 [2048][1024]
#define VT_OFF   ((size_t)8388608)    // V^T [512][2048]
#define WT_BASE  ((size_t)9437184)
#define WTK_OFF  (WT_BASE)                       // [1024][512]
#define WTQ_OFF  (WT_BASE + (size_t)524288)
#define WTG1_OFF (WT_BASE + (size_t)1048576)
#define WTG2_OFF (WT_BASE + (size_t)1572864)
#define WTV_OFF  (WT_BASE + (size_t)2097152)     // [512][512]
// After proj, the WT region is dead -> reuse for attention partials:
#define NUM0_OFF (WT_BASE)                       // bf16 [2048][512] (n-split 0)
#define NUM1_OFF (WT_BASE + (size_t)1048576)     // bf16 [2048][512] (n-split 1)
#define DEN_OFF  (WT_BASE + (size_t)2097152)     // f32  [2][8][2048] (as raw bytes)
#define VSUM_OFF (DEN_OFF + (size_t)65536)       // f32  [512] column sums of V
// total ws: 11,796,480 bf16 elems = 23.6 MB (unchanged)

// LDS XOR swizzles (byte-address based, applied identically on write & read)
#define KSWZ(r, cB) ((((r) * 256) + (cB)) ^ ((((r) & 7)) << 4))   // [64][128] bf16 tiles
#define PSWZ(r, cB) ((((r) * 128) + (cB)) ^ ((((r) & 7)) << 4))   // [16][64] bf16 tile
#define VSWZ(r, cB) ((((r) * 128) + (cB)) ^ ((((r) & 7)) << 4))   // [64][64] bf16 tile

// Transpose + convert W[k][n] fp32 -> Wt[n][k] bf16, all 5 weights in one launch.
__global__ __launch_bounds__(256)
void wtrans_kernel(const float* __restrict__ WK, const float* __restrict__ WQ,
                   const float* __restrict__ WG1, const float* __restrict__ WG2,
                   const float* __restrict__ WV, bf16* __restrict__ ws)
{
  __shared__ float T[32][33];
  const float* W; unsigned short* Wt; int N;
  switch (blockIdx.z) {
    case 0:  W = WK;  Wt = (unsigned short*)(ws + WTK_OFF);  N = 1024; break;
    case 1:  W = WQ;  Wt = (unsigned short*)(ws + WTQ_OFF);  N = 1024; break;
    case 2:  W = WG1; Wt = (unsigned short*)(ws + WTG1_OFF); N = 1024; break;
    case 3:  W = WG2; Wt = (unsigned short*)(ws + WTG2_OFF); N = 1024; break;
    default: W = WV;  Wt = (unsigned short*)(ws + WTV_OFF);  N = 512;  break;
  }
  int n0 = blockIdx.x * 32, k0 = blockIdx.y * 32;
  if (n0 >= N) return;
  int tid = threadIdx.x;
  int kk = tid >> 3, nn = (tid & 7) * 4;
  float4 v = *(const float4*)(W + (size_t)(k0 + kk) * N + n0 + nn);
  T[kk][nn] = v.x; T[kk][nn + 1] = v.y; T[kk][nn + 2] = v.z; T[kk][nn + 3] = v.w;
  __syncthreads();
  int n2 = tid >> 3, k2 = (tid & 7) * 4;
  uint2 pw;
  pw.x = pack2(T[k2][n2],     T[k2 + 1][n2]);
  pw.y = pack2(T[k2 + 2][n2], T[k2 + 3][n2]);
  *(uint2*)(Wt + (size_t)(n0 + n2) * 512 + k0 + k2) = pw;
}

// Batched MFMA projection GEMM (verified round 4).
__global__ __launch_bounds__(256)
void proj_mfma_kernel(const float* __restrict__ fa, const float* __restrict__ fp,
                      const float* __restrict__ sa, const float* __restrict__ sp,
                      const float* __restrict__ bKp, const float* __restrict__ bQp,
                      const float* __restrict__ bG1p, const float* __restrict__ bG2p,
                      const float* __restrict__ bVp, bf16* __restrict__ ws)
{
  __shared__ short Xs[128][40];
  __shared__ short Wsh[128][40];
  const float* X; const unsigned short* Wt; const float* bias; unsigned short* C;
  int N; bool trans = false;
  switch (blockIdx.z) {
    case 0:  X = fa; Wt = (const unsigned short*)(ws + WTK_OFF);  bias = bKp;  C = (unsigned short*)(ws + KB_OFF); N = 1024; break;
    case 1:  X = sa; Wt = (const unsigned short*)(ws + WTQ_OFF);  bias = bQp;  C = (unsigned short*)(ws + QB_OFF); N = 1024; break;
    case 2:  X = fp; Wt = (const unsigned short*)(ws + WTG1_OFF); bias = bG1p; C = (unsigned short*)(ws + G1_OFF); N = 1024; break;
    case 3:  X = sp; Wt = (const unsigned short*)(ws + WTG2_OFF); bias = bG2p; C = (unsigned short*)(ws + G2_OFF); N = 1024; break;
    default: X = fa; Wt = (const unsigned short*)(ws + WTV_OFF);  bias = bVp;  C = (unsigned short*)(ws + VT_OFF); N = 512; trans = true; break;
  }
  const int n0 = blockIdx.x * 128;
  if (n0 >= N) return;
  const int m0 = blockIdx.y * 128;
  const int tid = threadIdx.x;
  const int w = tid >> 6, l = tid & 63, l15 = l & 15, l4 = l >> 4;
  const int wm = (w & 1) * 64, wn = (w >> 1) * 64;
  const int srow = tid >> 1, shalf = (tid & 1) * 16;

  const float* xp = X + (size_t)(m0 + srow) * 512 + shalf;
  const unsigned short* wp = Wt + (size_t)(n0 + srow) * 512 + shalf;

  const f32x4 zero = {0.f, 0.f, 0.f, 0.f};
  f32x4 acc[4][4];
#pragma unroll
  for (int i = 0; i < 4; ++i)
#pragma unroll
    for (int j = 0; j < 4; ++j) acc[i][j] = zero;

  float4 px[4]; uint4 pw0, pw1;
  auto ldg = [&](int kc) {
    px[0] = *(const float4*)(xp + kc);
    px[1] = *(const float4*)(xp + kc + 4);
    px[2] = *(const float4*)(xp + kc + 8);
    px[3] = *(const float4*)(xp + kc + 12);
    pw0 = *(const uint4*)(wp + kc);
    pw1 = *(const uint4*)(wp + kc + 8);
  };
  ldg(0);

  for (int kc = 0; kc < 512; kc += 32) {
    __syncthreads();
    uint4 xa, xb;
    xa.x = pack2(px[0].x, px[0].y); xa.y = pack2(px[0].z, px[0].w);
    xa.z = pack2(px[1].x, px[1].y); xa.w = pack2(px[1].z, px[1].w);
    xb.x = pack2(px[2].x, px[2].y); xb.y = pack2(px[2].z, px[2].w);
    xb.z = pack2(px[3].x, px[3].y); xb.w = pack2(px[3].z, px[3].w);
    *(uint4*)&Xs[srow][shalf]      = xa;
    *(uint4*)&Xs[srow][shalf + 8]  = xb;
    *(uint4*)&Wsh[srow][shalf]     = pw0;
    *(uint4*)&Wsh[srow][shalf + 8] = pw1;
    __syncthreads();
    if (kc + 32 < 512) ldg(kc + 32);

    short8 xf[4], wf[4];
#pragma unroll
    for (int t = 0; t < 4; ++t) {
      xf[t] = *(const short8*)&Xs[wm + t * 16 + l15][l4 * 8];
      wf[t] = *(const short8*)&Wsh[wn + t * 16 + l15][l4 * 8];
    }
    if (!trans) {
#pragma unroll
      for (int i = 0; i < 4; ++i)
#pragma unroll
        for (int j = 0; j < 4; ++j)
          acc[i][j] = MFMA(wf[i], xf[j], acc[i][j]);   // D[n][m]
    } else {
#pragma unroll
      for (int i = 0; i < 4; ++i)
#pragma unroll
        for (int j = 0; j < 4; ++j)
          acc[i][j] = MFMA(xf[i], wf[j], acc[i][j]);   // D[m][n]
    }
  }

  if (!trans) {
#pragma unroll
    for (int tn = 0; tn < 4; ++tn) {
      float4 b4 = *(const float4*)(bias + n0 + wn + tn * 16 + l4 * 4);
#pragma unroll
      for (int tm = 0; tm < 4; ++tm) {
        uint2 pw;
        pw.x = pack2(acc[tn][tm][0] + b4.x, acc[tn][tm][1] + b4.y);
        pw.y = pack2(acc[tn][tm][2] + b4.z, acc[tn][tm][3] + b4.w);
        *(uint2*)(C + (size_t)(m0 + wm + tm * 16 + l15) * N + n0 + wn + tn * 16 + l4 * 4) = pw;
      }
    }
  } else {
#pragma unroll
    for (int tn = 0; tn < 4; ++tn) {
      float bn = bias[n0 + wn + tn * 16 + l15];
#pragma unroll
      for (int tm = 0; tm < 4; ++tm) {
        uint2 pw;
        pw.x = pack2(acc[tm][tn][0] + bn, acc[tm][tn][1] + bn);
        pw.y = pack2(acc[tm][tn][2] + bn, acc[tm][tn][3] + bn);
        *(uint2*)(C + (size_t)(n0 + wn + tn * 16 + l15) * 2048 + m0 + wm + tm * 16 + l4 * 4) = pw;
      }
    }
  }
}

// Column sums of V (= row sums of V^T [512][2048]) in f32. One wave per row.
__global__ __launch_bounds__(256)
void vsum_kernel(const bf16* __restrict__ Vtg, float* __restrict__ vs)
{
  const int row = blockIdx.x * 4 + (threadIdx.x >> 6);
  const int l = threadIdx.x & 63;
  const bf16* p = Vtg + (size_t)row * 2048 + l * 8;
  float s = 0.f;
#pragma unroll
  for (int c = 0; c < 4; ++c) {
    short8 v = *(const short8*)(p + c * 512);
#pragma unroll
    for (int j = 0; j < 8; ++j) s += b2f((unsigned short)v[j]);
  }
#pragma unroll
  for (int off = 32; off; off >>= 1) s += __shfl_xor(s, off, 64);
  if (l == 0) vs[row] = s;
}

// MFMA fused attention.
//  - Operand-swapped scores (round 0, kept): lane owns one m-row, P path is
//    4x ds_write_b64 + 2x ds_read_b128, scale is a per-lane register.
//  - V re-staged in LDS with tile-ahead prefetch (round 0's global-V reads were
//    latency-bound at 2 waves/SIMD: +15us regression. Reverted.)
//  - XCD-aware block remap: all 32 m-tiles of 2 consecutive (h,split) groups land
//    on one XCD -> 1MB K/G working set per XCD L2 (was 45MB HBM re-fetch).
//  - s_setprio(1) around MFMA clusters (T5).
//  - LDS 49152 B; occupancy is grid-limited at 2 blocks/CU (512 blocks).
__global__ __launch_bounds__(256)
void attn_mfma_kernel(const bf16* __restrict__ Kb, const bf16* __restrict__ G1b,
                      const bf16* __restrict__ Vtg, const bf16* __restrict__ Qb,
                      const bf16* __restrict__ G2b, bf16* __restrict__ ws)
{
  __shared__ short Ks[64][128];
  __shared__ short G1s[64][128];
  __shared__ short Vts[64][64];
  __shared__ short Ps[4][16][64];

  const int tid = threadIdx.x;
  const int w   = tid >> 6;
  const int l   = tid & 63;
  const int l15 = l & 15;
  const int l4  = l >> 4;

  // XCD-aware remap: hardware round-robins consecutive flat ids across 8 XCDs.
  // vid = (f&7)*64 + (f>>3) gives each XCD 64 consecutive vids = all 32 m-tiles
  // of 2 (h,split) groups -> K/G stream stays L2-resident.
  const int f = blockIdx.x + blockIdx.y * 32 + blockIdx.z * 256;  // grid (32,8,2)
  const int vid = (f & 7) * 64 + (f >> 3);
  const int m0    = (vid & 31) * 64;
  const int grp   = vid >> 5;
  const int h     = grp & 7;
  const int split = grp >> 3;

  short8 qf[4], gf[4];
  {
    const size_t ro = (size_t)(m0 + w * 16 + l15) * 1024 + h * 128 + l4 * 8;
#pragma unroll
    for (int kk = 0; kk < 4; ++kk) {
      qf[kk] = *(const short8*)(Qb + ro + kk * 32);
      gf[kk] = *(const short8*)(G2b + ro + kk * 32);
    }
  }
  float sc;
  {
    float sq = 0.f, sg = 0.f;
#pragma unroll
    for (int kk = 0; kk < 4; ++kk)
#pragma unroll
      for (int j = 0; j < 8; ++j) {
        float q = b2f((unsigned short)qf[kk][j]);
        float g = b2f((unsigned short)gf[kk][j]);
        sq += q * q; sg += g * g;
      }
    sq += __shfl_xor(sq, 16, 64); sq += __shfl_xor(sq, 32, 64);
    sg += __shfl_xor(sg, 16, 64); sg += __shfl_xor(sg, 32, 64);
    // per-lane scale for row m = w*16 + l15
    sc = rsqrtf(sq) * rsqrtf(sg) * (1.0f / 16384.0f);
  }

  const int r0  = tid >> 3;
  const int c0  = (tid & 7) * 16;    // shorts
  const int c0b = c0 * 2;            // bytes
  const int jv  = tid >> 2;          // V stage row (dv)
  const int nvB = (tid & 3) * 32;    // V stage col bytes

  short8 pk[4], pg[4], pv0, pv1;
  auto load_tile = [&](int nt) {     // nt in global 64-units
    const int n0 = nt * 64;
    const bf16* kp = Kb  + (size_t)(n0 + r0) * 1024 + h * 128 + c0;
    const bf16* gp = G1b + (size_t)(n0 + r0) * 1024 + h * 128 + c0;
    pk[0] = *(const short8*)(kp);
    pk[1] = *(const short8*)(kp + 8);
    pk[2] = *(const short8*)(kp + 32 * 1024);
    pk[3] = *(const short8*)(kp + 32 * 1024 + 8);
    pg[0] = *(const short8*)(gp);
    pg[1] = *(const short8*)(gp + 8);
    pg[2] = *(const short8*)(gp + 32 * 1024);
    pg[3] = *(const short8*)(gp + 32 * 1024 + 8);
    const bf16* vp = Vtg + (size_t)(h * 64 + jv) * 2048 + n0 + (tid & 3) * 16;
    pv0 = *(const short8*)(vp);
    pv1 = *(const short8*)(vp + 8);
  };
  const int ntbase = split * 16;
  load_tile(ntbase);

  const f32x4 zero = {0.f, 0.f, 0.f, 0.f};
  f32x4 accO[4], accD = zero;
#pragma unroll
  for (int t = 0; t < 4; ++t) accO[t] = zero;

  short8 ones;
#pragma unroll
  for (int j = 0; j < 8; ++j) ones[j] = (short)0x3F80;

  char* const ksb = (char*)&Ks[0][0];
  char* const g1p = (char*)&G1s[0][0];
  char* const vsb = (char*)&Vts[0][0];
  char* const psb = (char*)&Ps[w][0][0];

  for (int nt = 0; nt < 16; ++nt) {
    __syncthreads();
    *(short8*)(ksb + KSWZ(r0,      c0b))      = pk[0];
    *(short8*)(ksb + KSWZ(r0,      c0b + 16)) = pk[1];
    *(short8*)(ksb + KSWZ(r0 + 32, c0b))      = pk[2];
    *(short8*)(ksb + KSWZ(r0 + 32, c0b + 16)) = pk[3];
    *(short8*)(g1p + KSWZ(r0,      c0b))      = pg[0];
    *(short8*)(g1p + KSWZ(r0,      c0b + 16)) = pg[1];
    *(short8*)(g1p + KSWZ(r0 + 32, c0b))      = pg[2];
    *(short8*)(g1p + KSWZ(r0 + 32, c0b + 16)) = pg[3];
    *(short8*)(vsb + VSWZ(jv, nvB))           = pv0;
    *(short8*)(vsb + VSWZ(jv, nvB + 16))      = pv1;
    __syncthreads();
    if (nt + 1 < 16) load_tile(ntbase + nt + 1);

    // scores for this tile: swapped operands -> lane holds S[n-quads][m=l15]
#pragma unroll
    for (int t = 0; t < 4; ++t) {
      f32x4 sa = zero, sg2 = zero;
      __builtin_amdgcn_s_setprio(1);
#pragma unroll
      for (int kk = 0; kk < 4; ++kk) {
        short8 kbf = *(const short8*)(ksb + KSWZ(t * 16 + l15, kk * 64 + l4 * 16));
        sa  = MFMA(kbf, qf[kk], sa);
        short8 gbf = *(const short8*)(g1p + KSWZ(t * 16 + l15, kk * 64 + l4 * 16));
        sg2 = MFMA(gbf, gf[kk], sg2);
      }
      __builtin_amdgcn_s_setprio(0);
      // P' = exp(x)-1 ~= x + x^2/2 (|x| ~ 1e-4)
      float x0 = sa[0] * sg2[0] * sc;
      float x1 = sa[1] * sg2[1] * sc;
      float x2 = sa[2] * sg2[2] * sc;
      float x3 = sa[3] * sg2[3] * sc;
      float p0 = __builtin_fmaf(0.5f * x0, x0, x0);
      float p1 = __builtin_fmaf(0.5f * x1, x1, x1);
      float p2 = __builtin_fmaf(0.5f * x2, x2, x2);
      float p3 = __builtin_fmaf(0.5f * x3, x3, x3);
      uint2 pw;
      pw.x = pack_bf2(p0, p1);
      pw.y = pack_bf2(p2, p3);
      // Ps[m=l15][n = t*16 + l4*4 .. +3]
      *(uint2*)(psb + PSWZ(l15, t * 32 + l4 * 8)) = pw;
    }

    // PV + denominator from swizzled LDS V tile
#pragma unroll
    for (int ks = 0; ks < 2; ++ks) {
      short8 pf = *(const short8*)(psb + PSWZ(l15, ks * 64 + l4 * 16));
      __builtin_amdgcn_s_setprio(1);
      accD = MFMA(pf, ones, accD);
#pragma unroll
      for (int jt = 0; jt < 4; ++jt) {
        short8 vbf = *(const short8*)(vsb + VSWZ(jt * 16 + l15, ks * 64 + l4 * 16));
        accO[jt] = MFMA(pf, vbf, accO[jt]);
      }
      __builtin_amdgcn_s_setprio(0);
    }
  }

  // ---- write partials ----
  bf16* num = ws + (split ? NUM1_OFF : NUM0_OFF);
  float* den = (float*)(ws + DEN_OFF);
  if (l15 == 0) {
#pragma unroll
    for (int r = 0; r < 4; ++r)
      den[(size_t)(split * 8 + h) * 2048 + m0 + w * 16 + l4 * 4 + r] = accD[r];
  }
#pragma unroll
  for (int jt = 0; jt < 4; ++jt) {
#pragma unroll
    for (int r = 0; r < 4; ++r)
      num[(size_t)(m0 + w * 16 + l4 * 4 + r) * 512 + h * 64 + jt * 16 + l15]
        = __float2bfloat16(accO[jt][r]);
  }
}

// out[m][c] = (num0+num1+Vsum[c]) / (2048 + den0 + den1), 8 elems/thread
__global__ __launch_bounds__(256)
void combine_kernel(const bf16* __restrict__ ws, float* __restrict__ out)
{
  const unsigned short* num0 = (const unsigned short*)(ws + NUM0_OFF);
  const unsigned short* num1 = (const unsigned short*)(ws + NUM1_OFF);
  const float* den  = (const float*)(ws + DEN_OFF);
  const float* vsum = (const float*)(ws + VSUM_OFF);
  int idx = (blockIdx.x * 256 + threadIdx.x) * 8;
  int m = idx >> 9, c = idx & 511, h = c >> 6;
  float d = 2048.0f + den[(size_t)h * 2048 + m] + den[(size_t)(8 + h) * 2048 + m];
  float rd = 1.0f / d;
  short8 a = *(const short8*)(num0 + idx);
  short8 b = *(const short8*)(num1 + idx);
  float4 v0 = *(const float4*)(vsum + c);
  float4 v1 = *(const float4*)(vsum + c + 4);
  float vs[8] = {v0.x, v0.y, v0.z, v0.w, v1.x, v1.y, v1.z, v1.w};
  float r[8];
#pragma unroll
  for (int j = 0; j < 8; ++j)
    r[j] = (b2f((unsigned short)a[j]) + b2f((unsigned short)b[j]) + vs[j]) * rd;
  *(float4*)(out + idx)     = float4{r[0], r[1], r[2], r[3]};
  *(float4*)(out + idx + 4) = float4{r[4], r[5], r[6], r[7]};
}

extern "C" void kernel_launch(void* const* d_in, const int* in_sizes, int n_in,
                              void* d_out, int out_size, void* d_ws, size_t ws_size,
                              hipStream_t stream) {
  const float* first_app  = (const float*)d_in[0];
  const float* first_pos  = (const float*)d_in[1];
  const float* second_app = (const float*)d_in[2];
  const float* second_pos = (const float*)d_in[3];
  const float* WK  = (const float*)d_in[4];
  const float* bK  = (const float*)d_in[5];
  const float* WQ  = (const float*)d_in[6];
  const float* bQ  = (const float*)d_in[7];
  const float* WV  = (const float*)d_in[8];
  const float* bV  = (const float*)d_in[9];
  const float* WG1 = (const float*)d_in[10];
  const float* bG1 = (const float*)d_in[11];
  const float* WG2 = (const float*)d_in[12];
  const float* bG2 = (const float*)d_in[13];

  bf16* ws = (bf16*)d_ws;

  wtrans_kernel<<<dim3(32, 16, 5), 256, 0, stream>>>(WK, WQ, WG1, WG2, WV, ws);
  proj_mfma_kernel<<<dim3(8, 16, 5), 256, 0, stream>>>(
      first_app, first_pos, second_app, second_pos, bK, bQ, bG1, bG2, bV, ws);
  vsum_kernel<<<dim3(128), 256, 0, stream>>>(ws + VT_OFF, (float*)(ws + VSUM_OFF));
  attn_mfma_kernel<<<dim3(32, 8, 2), 256, 0, stream>>>(
      ws + KB_OFF, ws + G1_OFF, ws + VT_OFF, ws + QB_OFF, ws + G2_OFF, ws);
  combine_kernel<<<dim3(512), 256, 0, stream>>>(ws, (float*)d_out);
}